// Round 2
// baseline (1111.476 us; speedup 1.0000x reference)
//
#include <hip/hip_runtime.h>
#include <stdint.h>

#define TOKENS 8192
#define HIDDEN 1024
#define INTER  2816
#define NEXP   8

typedef float floatx4 __attribute__((ext_vector_type(4)));
typedef __bf16 bf16x8 __attribute__((ext_vector_type(8)));

__device__ __forceinline__ unsigned short f2bf(float f) {
  unsigned int u = __float_as_uint(f);
  u += 0x7fffu + ((u >> 16) & 1u);
  return (unsigned short)(u >> 16);
}

__device__ __forceinline__ void async16(const void* g, void* l) {
  __builtin_amdgcn_global_load_lds(
      (const __attribute__((address_space(1))) void*)g,
      (__attribute__((address_space(3))) void*)l, 16, 0, 0);
}

// ---------------- fp32 -> bf16 conversion (4 tensors, one launch) ----------------
__global__ void cvt_bf16_4(const float* __restrict__ s0, unsigned short* __restrict__ d0, int n0,
                           const float* __restrict__ s1, unsigned short* __restrict__ d1, int n1,
                           const float* __restrict__ s2, unsigned short* __restrict__ d2, int n2,
                           const float* __restrict__ s3, unsigned short* __restrict__ d3, int n3) {
  const float* s; unsigned short* d; int n;
  switch (blockIdx.z) {
    case 0: s = s0; d = d0; n = n0; break;
    case 1: s = s1; d = d1; n = n1; break;
    case 2: s = s2; d = d2; n = n2; break;
    default: s = s3; d = d3; n = n3; break;
  }
  int i = blockIdx.x * blockDim.x + threadIdx.x;
  int stride = gridDim.x * blockDim.x;
  for (; i < n; i += stride) {
    float4 v = ((const float4*)s)[i];
    ushort4 o;
    o.x = f2bf(v.x); o.y = f2bf(v.y); o.z = f2bf(v.z); o.w = f2bf(v.w);
    ((ushort4*)d)[i] = o;
  }
}

// ---------------- routing: logits -> top2 -> softmax ----------------
__global__ void moe_route(const float* __restrict__ hs,
                          const float* __restrict__ wg,
                          int* __restrict__ counts,
                          int* __restrict__ top_idx,
                          float* __restrict__ top_w) {
  const int token = blockIdx.x * 4 + (threadIdx.x >> 6);
  const int lane = threadIdx.x & 63;
  const float* row = hs + (size_t)token * HIDDEN;
  float acc[NEXP];
#pragma unroll
  for (int e = 0; e < NEXP; e++) acc[e] = 0.f;
  for (int j = lane; j < HIDDEN; j += 64) {
    float x = row[j];
#pragma unroll
    for (int e = 0; e < NEXP; e++) acc[e] += x * wg[e * HIDDEN + j];
  }
#pragma unroll
  for (int e = 0; e < NEXP; e++) {
    float v = acc[e];
    for (int off = 32; off > 0; off >>= 1) v += __shfl_down(v, off);
    acc[e] = v;
  }
  if (lane == 0) {
    int i0 = 0; float v0 = acc[0];
#pragma unroll
    for (int e = 1; e < NEXP; e++) if (acc[e] > v0) { v0 = acc[e]; i0 = e; }
    int i1 = -1; float v1 = -3.0e38f;
#pragma unroll
    for (int e = 0; e < NEXP; e++) if (e != i0 && acc[e] > v1) { v1 = acc[e]; i1 = e; }
    float e1 = __expf(v1 - v0);
    float s = 1.f + e1;
    top_idx[token * 2 + 0] = i0;
    top_idx[token * 2 + 1] = i1;
    top_w[token * 2 + 0] = 1.f / s;
    top_w[token * 2 + 1] = e1 / s;
    atomicAdd(&counts[i0], 1);
    atomicAdd(&counts[i1], 1);
  }
}

__global__ void moe_scan(const int* __restrict__ counts,
                         int* __restrict__ offsets, int* __restrict__ cursor) {
  if (threadIdx.x == 0) {
    int s = 0;
    for (int e = 0; e < NEXP; e++) { offsets[e] = s; cursor[e] = s; s += counts[e]; }
  }
}

__global__ void moe_assign(const int* __restrict__ top_idx,
                           const float* __restrict__ top_w,
                           int* __restrict__ cursor,
                           int* __restrict__ token_of,
                           float* __restrict__ wgt_of,
                           int* __restrict__ slot_of) {
  const int t = blockIdx.x * 256 + threadIdx.x;
#pragma unroll
  for (int k = 0; k < 2; k++) {
    int e = top_idx[t * 2 + k];
    int pos = atomicAdd(&cursor[e], 1);
    token_of[pos] = t;
    wgt_of[pos] = top_w[t * 2 + k];
    slot_of[t * 2 + k] = pos;
  }
}

// LDS layout (conflict-free): per 16-row block b (1024 B), element (row,k') lives at
//   b*512 + (k'>>3)*128 + (row&15)*8 + (k'&7)   [k' = k within 32-wide tile]
// Staged by global_load_lds: lane l of the wave loads (row=l&15, seg=l>>4) so the
// wave-contiguous LDS dest matches. Fragment read: 8 consecutive lanes cover all
// 32 banks exactly once -> no SQ_LDS_BANK_CONFLICT.

// ---------------- grouped GEMM A: act = silu(hs@WgT) * (hs@WuT) ----------------
__global__ __launch_bounds__(256, 2) void gemm_gateup(
    const unsigned short* __restrict__ hs_bf,
    const unsigned short* __restrict__ wg_bf,
    const unsigned short* __restrict__ wu_bf,
    const int* __restrict__ counts,
    const int* __restrict__ offsets,
    const int* __restrict__ token_of,
    unsigned short* __restrict__ act) {
  const int e = blockIdx.z;
  const int cnt = counts[e];
  const int mbase = blockIdx.y * 128;
  if (mbase >= cnt) return;
  const int off0 = offsets[e];
  const int ntile = blockIdx.x;

  __shared__ __align__(16) unsigned short sA[128 * 32];
  __shared__ __align__(16) unsigned short sBg[128 * 32];
  __shared__ __align__(16) unsigned short sBu[128 * 32];
  __shared__ int rb[128];

  const int tid = threadIdx.x;
  const int wave = tid >> 6;
  const int lane = tid & 63;

  if (tid < 128) {
    int slot = off0 + mbase + tid;
    int last = off0 + cnt - 1;
    if (slot > last) slot = last;
    rb[tid] = token_of[slot] * (HIDDEN * 2);
  }
  __syncthreads();

  const int r = lane & 15;
  const int sg = lane >> 4;       // k-seg 0..3
  const int colb = sg * 16;       // byte offset within the 64B k-chunk
  const char* pA = (const char*)hs_bf;
  const char* pBg = (const char*)wg_bf + (size_t)e * INTER * HIDDEN * 2;
  const char* pBu = (const char*)wu_bf + (size_t)e * INTER * HIDDEN * 2;
  const long aoff0 = (long)rb[wave * 16 + r] + colb;
  const long aoff1 = (long)rb[64 + wave * 16 + r] + colb;
  const long boff0 = (long)(ntile * 128 + wave * 16 + r) * (HIDDEN * 2) + colb;
  const long boff1 = (long)(ntile * 128 + 64 + wave * 16 + r) * (HIDDEN * 2) + colb;

  unsigned short* lA0 = &sA[wave * 512];
  unsigned short* lA1 = &sA[2048 + wave * 512];
  unsigned short* lBg0 = &sBg[wave * 512];
  unsigned short* lBg1 = &sBg[2048 + wave * 512];
  unsigned short* lBu0 = &sBu[wave * 512];
  unsigned short* lBu1 = &sBu[2048 + wave * 512];

  floatx4 accg[4][4], accu[4][4];
  const floatx4 zf = {0.f, 0.f, 0.f, 0.f};
#pragma unroll
  for (int i = 0; i < 4; i++)
#pragma unroll
    for (int j = 0; j < 4; j++) { accg[i][j] = zf; accu[i][j] = zf; }

  const int quad = lane >> 4;
  const int l16 = lane & 15;
  const int wm = (wave >> 1) * 64;
  const int wn = (wave & 1) * 64;
  const int ab = (wave >> 1) * 4;   // A block base (16-row blocks)
  const int bb = (wave & 1) * 4;    // B block base

  for (int kk = 0; kk < HIDDEN / 32; kk++) {
    const int kb = kk * 64;
    __syncthreads();
    async16(pA + aoff0 + kb, lA0);
    async16(pA + aoff1 + kb, lA1);
    async16(pBg + boff0 + kb, lBg0);
    async16(pBg + boff1 + kb, lBg1);
    async16(pBu + boff0 + kb, lBu0);
    async16(pBu + boff1 + kb, lBu1);
    __syncthreads();
    bf16x8 a[4], bg[4], bu[4];
#pragma unroll
    for (int i = 0; i < 4; i++) {
      a[i] = *(const bf16x8*)&sA[(ab + i) * 512 + quad * 128 + l16 * 8];
      bg[i] = *(const bf16x8*)&sBg[(bb + i) * 512 + quad * 128 + l16 * 8];
      bu[i] = *(const bf16x8*)&sBu[(bb + i) * 512 + quad * 128 + l16 * 8];
    }
#pragma unroll
    for (int i = 0; i < 4; i++)
#pragma unroll
      for (int j = 0; j < 4; j++) {
        accg[i][j] = __builtin_amdgcn_mfma_f32_16x16x32_bf16(a[i], bg[j], accg[i][j], 0, 0, 0);
        accu[i][j] = __builtin_amdgcn_mfma_f32_16x16x32_bf16(a[i], bu[j], accu[i][j], 0, 0, 0);
      }
  }

  const size_t actrow0 = (size_t)(off0 + mbase);
#pragma unroll
  for (int i = 0; i < 4; i++) {
#pragma unroll
    for (int rr = 0; rr < 4; rr++) {
      const int m = wm + i * 16 + quad * 4 + rr;
      if (mbase + m < cnt) {
        unsigned short* dst = act + (actrow0 + m) * INTER + ntile * 128 + wn + l16;
#pragma unroll
        for (int j = 0; j < 4; j++) {
          float g = accg[i][j][rr];
          float u = accu[i][j][rr];
          float s = g / (1.f + __expf(-g)) * u;
          dst[j * 16] = f2bf(s);
        }
      }
    }
  }
}

// ---------------- grouped GEMM B: slot_out[slot] = w * (act @ WdT) ----------------
__global__ __launch_bounds__(256, 2) void gemm_down(
    const unsigned short* __restrict__ act,
    const unsigned short* __restrict__ wd_bf,
    const int* __restrict__ counts,
    const int* __restrict__ offsets,
    const float* __restrict__ wgt_of,
    float* __restrict__ slot_out) {
  const int e = blockIdx.z;
  const int cnt = counts[e];
  const int mbase = blockIdx.y * 128;
  if (mbase >= cnt) return;
  const int off0 = offsets[e];
  const int ntile = blockIdx.x;

  __shared__ __align__(16) unsigned short sA[128 * 32];
  __shared__ __align__(16) unsigned short sB[128 * 32];
  __shared__ float wl[128];

  const int tid = threadIdx.x;
  const int wave = tid >> 6;
  const int lane = tid & 63;

  if (tid < 128) {
    int slot = off0 + mbase + tid;
    int last = off0 + cnt - 1;
    if (slot > last) slot = last;
    wl[tid] = wgt_of[slot];
  }
  __syncthreads();

  const int r = lane & 15;
  const int sg = lane >> 4;
  const int colb = sg * 16;
  const int last = off0 + cnt - 1;
  int s0 = off0 + mbase + wave * 16 + r; if (s0 > last) s0 = last;
  int s1 = off0 + mbase + 64 + wave * 16 + r; if (s1 > last) s1 = last;
  const char* pA = (const char*)act;
  const char* pB = (const char*)wd_bf + (size_t)e * HIDDEN * INTER * 2;
  const long aoff0 = (long)s0 * (INTER * 2) + colb;
  const long aoff1 = (long)s1 * (INTER * 2) + colb;
  const long boff0 = (long)(ntile * 128 + wave * 16 + r) * (INTER * 2) + colb;
  const long boff1 = (long)(ntile * 128 + 64 + wave * 16 + r) * (INTER * 2) + colb;

  unsigned short* lA0 = &sA[wave * 512];
  unsigned short* lA1 = &sA[2048 + wave * 512];
  unsigned short* lB0 = &sB[wave * 512];
  unsigned short* lB1 = &sB[2048 + wave * 512];

  floatx4 acc[4][4];
  const floatx4 zf = {0.f, 0.f, 0.f, 0.f};
#pragma unroll
  for (int i = 0; i < 4; i++)
#pragma unroll
    for (int j = 0; j < 4; j++) acc[i][j] = zf;

  const int quad = lane >> 4;
  const int l16 = lane & 15;
  const int wm = (wave >> 1) * 64;
  const int wn = (wave & 1) * 64;
  const int ab = (wave >> 1) * 4;
  const int bb = (wave & 1) * 4;

  for (int kk = 0; kk < INTER / 32; kk++) {
    const int kb = kk * 64;
    __syncthreads();
    async16(pA + aoff0 + kb, lA0);
    async16(pA + aoff1 + kb, lA1);
    async16(pB + boff0 + kb, lB0);
    async16(pB + boff1 + kb, lB1);
    __syncthreads();
    bf16x8 a[4], b[4];
#pragma unroll
    for (int i = 0; i < 4; i++) {
      a[i] = *(const bf16x8*)&sA[(ab + i) * 512 + quad * 128 + l16 * 8];
      b[i] = *(const bf16x8*)&sB[(bb + i) * 512 + quad * 128 + l16 * 8];
    }
#pragma unroll
    for (int i = 0; i < 4; i++)
#pragma unroll
      for (int j = 0; j < 4; j++)
        acc[i][j] = __builtin_amdgcn_mfma_f32_16x16x32_bf16(a[i], b[j], acc[i][j], 0, 0, 0);
  }

#pragma unroll
  for (int i = 0; i < 4; i++) {
#pragma unroll
    for (int rr = 0; rr < 4; rr++) {
      const int m = wm + i * 16 + quad * 4 + rr;
      if (mbase + m < cnt) {
        const float w = wl[m];
        float* dst = slot_out + (size_t)(off0 + mbase + m) * HIDDEN + ntile * 128 + wn + l16;
#pragma unroll
        for (int j = 0; j < 4; j++) dst[j * 16] = acc[i][j][rr] * w;
      }
    }
  }
}

// ---------------- combine: out[t] = slot_out[slotA] + slot_out[slotB] ----------------
__global__ void moe_combine(const float* __restrict__ slot_out,
                            const int* __restrict__ slot_of,
                            float* __restrict__ out) {
  const int idx = blockIdx.x * 256 + threadIdx.x;   // TOKENS*256 total
  const int t = idx >> 8;
  const int c4 = idx & 255;
  const int sa = slot_of[t * 2 + 0];
  const int sb = slot_of[t * 2 + 1];
  float4 a = ((const float4*)(slot_out + (size_t)sa * HIDDEN))[c4];
  float4 b = ((const float4*)(slot_out + (size_t)sb * HIDDEN))[c4];
  float4 o;
  o.x = a.x + b.x; o.y = a.y + b.y; o.z = a.z + b.z; o.w = a.w + b.w;
  ((float4*)(out + (size_t)t * HIDDEN))[c4] = o;
}

extern "C" void kernel_launch(void* const* d_in, const int* in_sizes, int n_in,
                              void* d_out, int out_size, void* d_ws, size_t ws_size,
                              hipStream_t stream) {
  const float* hs = (const float*)d_in[0];
  const float* wg = (const float*)d_in[1];
  const float* wgp = (const float*)d_in[2];
  const float* wup = (const float*)d_in[3];
  const float* wdp = (const float*)d_in[4];
  float* out = (float*)d_out;

  char* ws = (char*)d_ws;
  int* counts = (int*)(ws + 0);
  int* cursor = (int*)(ws + 256);
  int* offsets = (int*)(ws + 512);
  int* top_idx = (int*)(ws + 1024);
  float* top_w = (float*)(ws + 1024 + 65536);
  int* token_of = (int*)(ws + 1024 + 2 * 65536);
  float* wgt_of = (float*)(ws + 1024 + 3 * 65536);
  int* slot_of = (int*)(ws + 1024 + 4 * 65536);
  size_t base = 1024 + 5 * 65536;
  unsigned short* hs_bf = (unsigned short*)(ws + base);
  base += (size_t)TOKENS * HIDDEN * 2;
  unsigned short* wg_bf = (unsigned short*)(ws + base);
  base += (size_t)NEXP * INTER * HIDDEN * 2;
  unsigned short* wu_bf = (unsigned short*)(ws + base);
  base += (size_t)NEXP * INTER * HIDDEN * 2;
  unsigned short* wd_bf = (unsigned short*)(ws + base);
  base += (size_t)NEXP * HIDDEN * INTER * 2;
  unsigned short* act = (unsigned short*)(ws + base);
  // slot_out aliases wg_bf/wu_bf (dead after gemm_gateup): 67.1 MB <= 92.3 MB
  float* slot_out = (float*)wg_bf;

  hipMemsetAsync(d_ws, 0, 768, stream);

  cvt_bf16_4<<<dim3(2048, 1, 4), 256, 0, stream>>>(
      hs, hs_bf, TOKENS * HIDDEN / 4,
      wgp, wg_bf, NEXP * INTER * HIDDEN / 4,
      wup, wu_bf, NEXP * INTER * HIDDEN / 4,
      wdp, wd_bf, NEXP * HIDDEN * INTER / 4);

  moe_route<<<TOKENS / 4, 256, 0, stream>>>(hs, wg, counts, top_idx, top_w);
  moe_scan<<<1, 64, 0, stream>>>(counts, offsets, cursor);
  moe_assign<<<TOKENS / 256, 256, 0, stream>>>(top_idx, top_w, cursor, token_of, wgt_of, slot_of);

  dim3 g1(INTER / 128, TOKENS / 128, NEXP);
  gemm_gateup<<<g1, 256, 0, stream>>>(hs_bf, wg_bf, wu_bf, counts, offsets, token_of, act);
  dim3 g2(HIDDEN / 128, TOKENS / 128, NEXP);
  gemm_down<<<g2, 256, 0, stream>>>(act, wd_bf, counts, offsets, wgt_of, slot_out);
  moe_combine<<<TOKENS, 256, 0, stream>>>(slot_out, slot_of, out);
}

// Round 3
// 993.695 us; speedup vs baseline: 1.1185x; 1.1185x over previous
//
#include <hip/hip_runtime.h>
#include <stdint.h>

#define TOKENS 8192
#define HIDDEN 1024
#define INTER  2816
#define NEXP   8

typedef float floatx4 __attribute__((ext_vector_type(4)));
typedef __bf16 bf16x8 __attribute__((ext_vector_type(8)));

__device__ __forceinline__ unsigned short f2bf(float f) {
  unsigned int u = __float_as_uint(f);
  u += 0x7fffu + ((u >> 16) & 1u);
  return (unsigned short)(u >> 16);
}

__device__ __forceinline__ void async16(const void* g, void* l) {
  __builtin_amdgcn_global_load_lds(
      (const __attribute__((address_space(1))) void*)g,
      (__attribute__((address_space(3))) void*)l, 16, 0, 0);
}

// ---------------- fp32 -> bf16 conversion (4 tensors, one launch) ----------------
__global__ void cvt_bf16_4(const float* __restrict__ s0, unsigned short* __restrict__ d0, int n0,
                           const float* __restrict__ s1, unsigned short* __restrict__ d1, int n1,
                           const float* __restrict__ s2, unsigned short* __restrict__ d2, int n2,
                           const float* __restrict__ s3, unsigned short* __restrict__ d3, int n3) {
  const float* s; unsigned short* d; int n;
  switch (blockIdx.z) {
    case 0: s = s0; d = d0; n = n0; break;
    case 1: s = s1; d = d1; n = n1; break;
    case 2: s = s2; d = d2; n = n2; break;
    default: s = s3; d = d3; n = n3; break;
  }
  int i = blockIdx.x * blockDim.x + threadIdx.x;
  int stride = gridDim.x * blockDim.x;
  for (; i < n; i += stride) {
    float4 v = ((const float4*)s)[i];
    ushort4 o;
    o.x = f2bf(v.x); o.y = f2bf(v.y); o.z = f2bf(v.z); o.w = f2bf(v.w);
    ((ushort4*)d)[i] = o;
  }
}

// ---------------- routing: logits -> top2 -> softmax ----------------
__global__ void moe_route(const float* __restrict__ hs,
                          const float* __restrict__ wg,
                          int* __restrict__ counts,
                          int* __restrict__ top_idx,
                          float* __restrict__ top_w) {
  const int token = blockIdx.x * 4 + (threadIdx.x >> 6);
  const int lane = threadIdx.x & 63;
  const float* row = hs + (size_t)token * HIDDEN;
  float acc[NEXP];
#pragma unroll
  for (int e = 0; e < NEXP; e++) acc[e] = 0.f;
  for (int j = lane; j < HIDDEN; j += 64) {
    float x = row[j];
#pragma unroll
    for (int e = 0; e < NEXP; e++) acc[e] += x * wg[e * HIDDEN + j];
  }
#pragma unroll
  for (int e = 0; e < NEXP; e++) {
    float v = acc[e];
    for (int off = 32; off > 0; off >>= 1) v += __shfl_down(v, off);
    acc[e] = v;
  }
  if (lane == 0) {
    int i0 = 0; float v0 = acc[0];
#pragma unroll
    for (int e = 1; e < NEXP; e++) if (acc[e] > v0) { v0 = acc[e]; i0 = e; }
    int i1 = -1; float v1 = -3.0e38f;
#pragma unroll
    for (int e = 0; e < NEXP; e++) if (e != i0 && acc[e] > v1) { v1 = acc[e]; i1 = e; }
    float e1 = __expf(v1 - v0);
    float s = 1.f + e1;
    top_idx[token * 2 + 0] = i0;
    top_idx[token * 2 + 1] = i1;
    top_w[token * 2 + 0] = 1.f / s;
    top_w[token * 2 + 1] = e1 / s;
    atomicAdd(&counts[i0], 1);
    atomicAdd(&counts[i1], 1);
  }
}

__global__ void moe_scan(const int* __restrict__ counts,
                         int* __restrict__ offsets, int* __restrict__ cursor) {
  if (threadIdx.x == 0) {
    int s = 0;
    for (int e = 0; e < NEXP; e++) { offsets[e] = s; cursor[e] = s; s += counts[e]; }
  }
}

__global__ void moe_assign(const int* __restrict__ top_idx,
                           const float* __restrict__ top_w,
                           int* __restrict__ cursor,
                           int* __restrict__ token_of,
                           float* __restrict__ wgt_of,
                           int* __restrict__ slot_of) {
  const int t = blockIdx.x * 256 + threadIdx.x;
#pragma unroll
  for (int k = 0; k < 2; k++) {
    int e = top_idx[t * 2 + k];
    int pos = atomicAdd(&cursor[e], 1);
    token_of[pos] = t;
    wgt_of[pos] = top_w[t * 2 + k];
    slot_of[t * 2 + k] = pos;
  }
}

// LDS layout: per 16-row block (1024 B), element (row, seg[16B]) lives at
//   64*row + 16*(seg ^ (row>>2)).
// Staging (coalesced, round-1 pattern): lane l -> LDS slot 16*l -> (row=l>>2,
//   global seg = (l&3)^(l>>4)); each aligned group of 4 lanes covers one
//   contiguous 64B global chunk (permuted quarters -> still one cache line).
// Fragment read: lane reads 64*l16 + 16*(quad^(l16>>2)) -> every bank hit
//   exactly 2x per phase; 2-way is free on gfx950 (m136).

// ---------------- grouped GEMM A: act = silu(hs@WgT) * (hs@WuT) ----------------
__global__ __launch_bounds__(256, 2) void gemm_gateup(
    const unsigned short* __restrict__ hs_bf,
    const unsigned short* __restrict__ wg_bf,
    const unsigned short* __restrict__ wu_bf,
    const int* __restrict__ counts,
    const int* __restrict__ offsets,
    const int* __restrict__ token_of,
    unsigned short* __restrict__ act) {
  const int e = blockIdx.z;
  const int cnt = counts[e];
  const int mbase = blockIdx.y * 128;
  if (mbase >= cnt) return;
  const int off0 = offsets[e];
  const int ntile = blockIdx.x;

  __shared__ __align__(16) unsigned short sA[128 * 32];
  __shared__ __align__(16) unsigned short sBg[128 * 32];
  __shared__ __align__(16) unsigned short sBu[128 * 32];
  __shared__ int rb[128];

  const int tid = threadIdx.x;
  const int wave = tid >> 6;
  const int lane = tid & 63;

  if (tid < 128) {
    int slot = off0 + mbase + tid;
    int last = off0 + cnt - 1;
    if (slot > last) slot = last;
    rb[tid] = token_of[slot] * (HIDDEN * 2);
  }
  __syncthreads();

  const int srow0 = wave * 16 + (lane >> 2);
  const int srow1 = srow0 + 64;
  const int colswz = (((lane & 3) ^ (lane >> 4))) * 16;   // swizzled 16B quarter
  const char* pA = (const char*)hs_bf;
  const char* pBg = (const char*)wg_bf + (size_t)e * INTER * HIDDEN * 2;
  const char* pBu = (const char*)wu_bf + (size_t)e * INTER * HIDDEN * 2;
  const long aoff0 = (long)rb[srow0] + colswz;
  const long aoff1 = (long)rb[srow1] + colswz;
  const long boff0 = (long)(ntile * 128 + srow0) * (HIDDEN * 2) + colswz;
  const long boff1 = (long)(ntile * 128 + 64 + srow0 - 64 + 64) * 0 +
                     (long)(ntile * 128 + srow1) * (HIDDEN * 2) + colswz;

  unsigned short* lA0 = &sA[wave * 512];
  unsigned short* lA1 = &sA[2048 + wave * 512];
  unsigned short* lBg0 = &sBg[wave * 512];
  unsigned short* lBg1 = &sBg[2048 + wave * 512];
  unsigned short* lBu0 = &sBu[wave * 512];
  unsigned short* lBu1 = &sBu[2048 + wave * 512];

  floatx4 accg[4][4], accu[4][4];
  const floatx4 zf = {0.f, 0.f, 0.f, 0.f};
#pragma unroll
  for (int i = 0; i < 4; i++)
#pragma unroll
    for (int j = 0; j < 4; j++) { accg[i][j] = zf; accu[i][j] = zf; }

  const int quad = lane >> 4;
  const int l16 = lane & 15;
  const int wm = (wave >> 1) * 64;
  const int wn = (wave & 1) * 64;
  const int ab = (wave >> 1) * 4;   // A 16-row block base
  const int bb = (wave & 1) * 4;    // B 16-row block base
  const int frg = l16 * 32 + (quad ^ (l16 >> 2)) * 8;  // swizzled fragment offset (elems)

  for (int kk = 0; kk < HIDDEN / 32; kk++) {
    const int kb = kk * 64;
    __syncthreads();
    async16(pA + aoff0 + kb, lA0);
    async16(pA + aoff1 + kb, lA1);
    async16(pBg + boff0 + kb, lBg0);
    async16(pBg + boff1 + kb, lBg1);
    async16(pBu + boff0 + kb, lBu0);
    async16(pBu + boff1 + kb, lBu1);
    __syncthreads();
    bf16x8 a[4], bg[4], bu[4];
#pragma unroll
    for (int i = 0; i < 4; i++) {
      a[i] = *(const bf16x8*)&sA[(ab + i) * 512 + frg];
      bg[i] = *(const bf16x8*)&sBg[(bb + i) * 512 + frg];
      bu[i] = *(const bf16x8*)&sBu[(bb + i) * 512 + frg];
    }
#pragma unroll
    for (int i = 0; i < 4; i++)
#pragma unroll
      for (int j = 0; j < 4; j++) {
        accg[i][j] = __builtin_amdgcn_mfma_f32_16x16x32_bf16(a[i], bg[j], accg[i][j], 0, 0, 0);
        accu[i][j] = __builtin_amdgcn_mfma_f32_16x16x32_bf16(a[i], bu[j], accu[i][j], 0, 0, 0);
      }
  }

  const size_t actrow0 = (size_t)(off0 + mbase);
#pragma unroll
  for (int i = 0; i < 4; i++) {
#pragma unroll
    for (int rr = 0; rr < 4; rr++) {
      const int m = wm + i * 16 + quad * 4 + rr;
      if (mbase + m < cnt) {
        unsigned short* dst = act + (actrow0 + m) * INTER + ntile * 128 + wn + l16;
#pragma unroll
        for (int j = 0; j < 4; j++) {
          float g = accg[i][j][rr];
          float u = accu[i][j][rr];
          float s = g / (1.f + __expf(-g)) * u;
          dst[j * 16] = f2bf(s);
        }
      }
    }
  }
}

// ---------------- grouped GEMM B: slot_out[slot] = w * (act @ WdT) ----------------
__global__ __launch_bounds__(256, 2) void gemm_down(
    const unsigned short* __restrict__ act,
    const unsigned short* __restrict__ wd_bf,
    const int* __restrict__ counts,
    const int* __restrict__ offsets,
    const float* __restrict__ wgt_of,
    float* __restrict__ slot_out) {
  const int e = blockIdx.z;
  const int cnt = counts[e];
  const int mbase = blockIdx.y * 128;
  if (mbase >= cnt) return;
  const int off0 = offsets[e];
  const int ntile = blockIdx.x;

  __shared__ __align__(16) unsigned short sA[128 * 32];
  __shared__ __align__(16) unsigned short sB[128 * 32];
  __shared__ float wl[128];

  const int tid = threadIdx.x;
  const int wave = tid >> 6;
  const int lane = tid & 63;

  if (tid < 128) {
    int slot = off0 + mbase + tid;
    int last = off0 + cnt - 1;
    if (slot > last) slot = last;
    wl[tid] = wgt_of[slot];
  }
  __syncthreads();

  const int srow0 = wave * 16 + (lane >> 2);
  const int srow1 = srow0 + 64;
  const int colswz = (((lane & 3) ^ (lane >> 4))) * 16;
  const int last = off0 + cnt - 1;
  int s0 = off0 + mbase + srow0; if (s0 > last) s0 = last;
  int s1 = off0 + mbase + srow1; if (s1 > last) s1 = last;
  const char* pA = (const char*)act;
  const char* pB = (const char*)wd_bf + (size_t)e * HIDDEN * INTER * 2;
  const long aoff0 = (long)s0 * (INTER * 2) + colswz;
  const long aoff1 = (long)s1 * (INTER * 2) + colswz;
  const long boff0 = (long)(ntile * 128 + srow0) * (INTER * 2) + colswz;
  const long boff1 = (long)(ntile * 128 + srow1) * (INTER * 2) + colswz;

  unsigned short* lA0 = &sA[wave * 512];
  unsigned short* lA1 = &sA[2048 + wave * 512];
  unsigned short* lB0 = &sB[wave * 512];
  unsigned short* lB1 = &sB[2048 + wave * 512];

  floatx4 acc[4][4];
  const floatx4 zf = {0.f, 0.f, 0.f, 0.f};
#pragma unroll
  for (int i = 0; i < 4; i++)
#pragma unroll
    for (int j = 0; j < 4; j++) acc[i][j] = zf;

  const int quad = lane >> 4;
  const int l16 = lane & 15;
  const int wm = (wave >> 1) * 64;
  const int wn = (wave & 1) * 64;
  const int ab = (wave >> 1) * 4;
  const int bb = (wave & 1) * 4;
  const int frg = l16 * 32 + (quad ^ (l16 >> 2)) * 8;

  for (int kk = 0; kk < INTER / 32; kk++) {
    const int kb = kk * 64;
    __syncthreads();
    async16(pA + aoff0 + kb, lA0);
    async16(pA + aoff1 + kb, lA1);
    async16(pB + boff0 + kb, lB0);
    async16(pB + boff1 + kb, lB1);
    __syncthreads();
    bf16x8 a[4], b[4];
#pragma unroll
    for (int i = 0; i < 4; i++) {
      a[i] = *(const bf16x8*)&sA[(ab + i) * 512 + frg];
      b[i] = *(const bf16x8*)&sB[(bb + i) * 512 + frg];
    }
#pragma unroll
    for (int i = 0; i < 4; i++)
#pragma unroll
      for (int j = 0; j < 4; j++)
        acc[i][j] = __builtin_amdgcn_mfma_f32_16x16x32_bf16(a[i], b[j], acc[i][j], 0, 0, 0);
  }

#pragma unroll
  for (int i = 0; i < 4; i++) {
#pragma unroll
    for (int rr = 0; rr < 4; rr++) {
      const int m = wm + i * 16 + quad * 4 + rr;
      if (mbase + m < cnt) {
        const float w = wl[m];
        float* dst = slot_out + (size_t)(off0 + mbase + m) * HIDDEN + ntile * 128 + wn + l16;
#pragma unroll
        for (int j = 0; j < 4; j++) dst[j * 16] = acc[i][j][rr] * w;
      }
    }
  }
}

// ---------------- combine: out[t] = slot_out[slotA] + slot_out[slotB] ----------------
__global__ void moe_combine(const float* __restrict__ slot_out,
                            const int* __restrict__ slot_of,
                            float* __restrict__ out) {
  const int idx = blockIdx.x * 256 + threadIdx.x;   // TOKENS*256 total
  const int t = idx >> 8;
  const int c4 = idx & 255;
  const int sa = slot_of[t * 2 + 0];
  const int sb = slot_of[t * 2 + 1];
  float4 a = ((const float4*)(slot_out + (size_t)sa * HIDDEN))[c4];
  float4 b = ((const float4*)(slot_out + (size_t)sb * HIDDEN))[c4];
  float4 o;
  o.x = a.x + b.x; o.y = a.y + b.y; o.z = a.z + b.z; o.w = a.w + b.w;
  ((float4*)(out + (size_t)t * HIDDEN))[c4] = o;
}

extern "C" void kernel_launch(void* const* d_in, const int* in_sizes, int n_in,
                              void* d_out, int out_size, void* d_ws, size_t ws_size,
                              hipStream_t stream) {
  const float* hs = (const float*)d_in[0];
  const float* wg = (const float*)d_in[1];
  const float* wgp = (const float*)d_in[2];
  const float* wup = (const float*)d_in[3];
  const float* wdp = (const float*)d_in[4];
  float* out = (float*)d_out;

  char* ws = (char*)d_ws;
  int* counts = (int*)(ws + 0);
  int* cursor = (int*)(ws + 256);
  int* offsets = (int*)(ws + 512);
  int* top_idx = (int*)(ws + 1024);
  float* top_w = (float*)(ws + 1024 + 65536);
  int* token_of = (int*)(ws + 1024 + 2 * 65536);
  float* wgt_of = (float*)(ws + 1024 + 3 * 65536);
  int* slot_of = (int*)(ws + 1024 + 4 * 65536);
  size_t base = 1024 + 5 * 65536;
  unsigned short* hs_bf = (unsigned short*)(ws + base);
  base += (size_t)TOKENS * HIDDEN * 2;
  unsigned short* wg_bf = (unsigned short*)(ws + base);
  base += (size_t)NEXP * INTER * HIDDEN * 2;
  unsigned short* wu_bf = (unsigned short*)(ws + base);
  base += (size_t)NEXP * INTER * HIDDEN * 2;
  unsigned short* wd_bf = (unsigned short*)(ws + base);
  base += (size_t)NEXP * HIDDEN * INTER * 2;
  unsigned short* act = (unsigned short*)(ws + base);
  // slot_out aliases wg_bf/wu_bf (dead after gemm_gateup): 67.1 MB <= 92.3 MB
  float* slot_out = (float*)wg_bf;

  hipMemsetAsync(d_ws, 0, 768, stream);

  cvt_bf16_4<<<dim3(2048, 1, 4), 256, 0, stream>>>(
      hs, hs_bf, TOKENS * HIDDEN / 4,
      wgp, wg_bf, NEXP * INTER * HIDDEN / 4,
      wup, wu_bf, NEXP * INTER * HIDDEN / 4,
      wdp, wd_bf, NEXP * HIDDEN * INTER / 4);

  moe_route<<<TOKENS / 4, 256, 0, stream>>>(hs, wg, counts, top_idx, top_w);
  moe_scan<<<1, 64, 0, stream>>>(counts, offsets, cursor);
  moe_assign<<<TOKENS / 256, 256, 0, stream>>>(top_idx, top_w, cursor, token_of, wgt_of, slot_of);

  dim3 g1(INTER / 128, TOKENS / 128, NEXP);
  gemm_gateup<<<g1, 256, 0, stream>>>(hs_bf, wg_bf, wu_bf, counts, offsets, token_of, act);
  dim3 g2(HIDDEN / 128, TOKENS / 128, NEXP);
  gemm_down<<<g2, 256, 0, stream>>>(act, wd_bf, counts, offsets, wgt_of, slot_out);
  moe_combine<<<TOKENS, 256, 0, stream>>>(slot_out, slot_of, out);
}